// Round 2
// baseline (153.975 us; speedup 1.0000x reference)
//
#include <hip/hip_runtime.h>
#include <hip/hip_bf16.h>

#define NN 8192
#define DD 128
#define NCH 8              // column chunks per row-strip
#define CCOLS (NN / NCH)   // 1024 cols per block
#define NTILE (CCOLS / 64) // 16 tiles of 64 cols

typedef short short8 __attribute__((ext_vector_type(8)));
typedef __bf16 bf16x8 __attribute__((ext_vector_type(8)));
typedef float f32x4 __attribute__((ext_vector_type(4)));

// ---------------- prep: normalize rows, write bf16 f and fp32 n2 ----------------
__global__ __launch_bounds__(256) void prep_kernel(const float* __restrict__ x,
                                                   __hip_bfloat16* __restrict__ fb,
                                                   float* __restrict__ n2) {
  int wave = threadIdx.x >> 6;
  int lane = threadIdx.x & 63;
  int row = blockIdx.x * 4 + wave;
  const float2 v = *(const float2*)(x + (size_t)row * DD + lane * 2);
  float ss = v.x * v.x + v.y * v.y;
  for (int off = 32; off; off >>= 1) ss += __shfl_xor(ss, off, 64);
  float nrm = fmaxf(sqrtf(ss), 1e-12f);
  float fx = v.x / nrm, fy = v.y / nrm;
  float s2 = fx * fx + fy * fy;
  for (int off = 32; off; off >>= 1) s2 += __shfl_xor(s2, off, 64);
  __hip_bfloat162 h;
  h.x = __float2bfloat16(fx);
  h.y = __float2bfloat16(fy);
  *(__hip_bfloat162*)(fb + (size_t)row * DD + lane * 2) = h;
  if (lane == 0) n2[row] = s2;
}

// ---------------- fused Gram + hyperbolic distance + masked row sums ----------------
__global__ __launch_bounds__(256) void fused_kernel(
    const __hip_bfloat16* __restrict__ fbg, const float* __restrict__ n2g,
    const int* __restrict__ plab, const int* __restrict__ slab,
    float* __restrict__ totg, float* __restrict__ tposg, float* __restrict__ npg) {
  // kk-blocked LDS layout: 16B unit index u = kk*256 + row*4 + quad
  // holds f[row][kk*32 + quad*8 .. +7]
  __shared__ short Abuf[64 * 128];
  __shared__ short Bbuf[64 * 128];
  __shared__ float n2c[64];
  __shared__ int plc[64], slc[64];

  const int tid = threadIdx.x;
  const int w = tid >> 6;
  const int lane = tid & 63;
  const int lrow = lane & 15;
  const int quad = lane >> 4;
  const int R0 = blockIdx.y * 64;
  const int C0 = blockIdx.x * CCOLS;

  const float c = 0.05f;
  const float SQRT_C = 0.223606797749979f;
  const float KE = -1.0f / (0.223606797749979f * 0.5f);   // -1/(sqrt_c*T)
  const float KL = KE * 0.6931471805599453f;              // KE*ln2

  // stage A block (rows R0..R0+63, all K) into LDS
  {
    const short* ga = (const short*)fbg + (size_t)R0 * DD;
    for (int i = 0; i < 4; i++) {
      int o = tid + i * 256;           // global 16B-unit index in row-major tile
      int grow = o >> 4, k8 = o & 15;
      int u = ((k8 >> 2) << 8) + (grow << 2) + (k8 & 3);
      *(short8*)(Abuf + u * 8) = *(const short8*)(ga + o * 8);
    }
  }

  // row-side constants (fixed per lane for whole kernel)
  float y2r[4];
  int plr[4], slr[4], rowg[4];
  for (int r = 0; r < 4; r++) {
    rowg[r] = R0 + w * 16 + quad * 4 + r;
    y2r[r] = n2g[rowg[r]];
    plr[r] = plab[rowg[r]];
    slr[r] = slab[rowg[r]];
  }

  float tot[4] = {0.f, 0.f, 0.f, 0.f};
  float tps[4] = {0.f, 0.f, 0.f, 0.f};
  float npp[4] = {0.f, 0.f, 0.f, 0.f};

  for (int tile = 0; tile < NTILE; tile++) {
    const int CT = C0 + tile * 64;
    __syncthreads();  // previous tile's readers done before overwriting Bbuf
    {
      const short* gb = (const short*)fbg + (size_t)CT * DD;
      for (int i = 0; i < 4; i++) {
        int o = tid + i * 256;
        int grow = o >> 4, k8 = o & 15;
        int u = ((k8 >> 2) << 8) + (grow << 2) + (k8 & 3);
        *(short8*)(Bbuf + u * 8) = *(const short8*)(gb + o * 8);
      }
      if (tid < 64) {
        n2c[tid] = n2g[CT + tid];
        plc[tid] = plab[CT + tid];
        slc[tid] = slab[CT + tid];
      }
    }
    __syncthreads();

    // A fragments for this wave's 16-row strip
    bf16x8 af[4];
    for (int kk = 0; kk < 4; kk++) {
      int u = (kk << 8) + ((w * 16 + lrow) << 2) + quad;
      short8 t = *(const short8*)(Abuf + u * 8);
      af[kk] = __builtin_bit_cast(bf16x8, t);
    }

    for (int ct = 0; ct < 4; ct++) {
      f32x4 acc = {0.f, 0.f, 0.f, 0.f};
      for (int kk = 0; kk < 4; kk++) {
        int u = (kk << 8) + ((ct * 16 + lrow) << 2) + quad;
        short8 t = *(const short8*)(Bbuf + u * 8);
        bf16x8 bfr = __builtin_bit_cast(bf16x8, t);
        acc = __builtin_amdgcn_mfma_f32_16x16x32_bf16(af[kk], bfr, acc, 0, 0, 0);
      }
      // elementwise hyperbolic distance + masked accumulation
      const int colg = CT + ct * 16 + lrow;
      const float x2 = n2c[ct * 16 + lrow];
      const int pc = plc[ct * 16 + lrow];
      const int sc = slc[ct * 16 + lrow];
      for (int r = 0; r < 4; r++) {
        float s = acc[r];
        float xy = -s;
        float y2 = y2r[r];
        float A = fmaf(c, fmaf(2.0f, xy, y2), 1.0f);
        float Bv = fmaf(-c, x2, 1.0f);
        float den = fmaf(2.0f * c, xy, fmaf(c * c, x2 * y2, 1.0f));
        den = fmaxf(den, 1e-15f);
        float AB = A * Bv;
        float num = fmaf(A * A, x2, fmaf(Bv * Bv, y2, 2.0f * xy * AB));
        num = fmaxf(num, 0.0f);
        float nd = SQRT_C * __builtin_amdgcn_sqrtf(num) * __builtin_amdgcn_rcpf(den);
        nd = fminf(nd, 1.0f - 1e-7f);
        float rr = (1.0f + nd) * __builtin_amdgcn_rcpf(1.0f - nd);
        float lg = __log2f(rr);
        float adc = KL * lg;       // -distance/T
        float e = __expf(adc);     // exp(adc)
        bool same = (pc == plr[r]) || (sc == slr[r]);
        bool offd = (colg != rowg[r]);
        tot[r] += offd ? e : 0.0f;
        bool p = same && offd;
        tps[r] += p ? adc : 0.0f;
        npp[r] += p ? 1.0f : 0.0f;
      }
    }
  }

  // reduce across the 16 lanes sharing each output row, then atomics
  for (int r = 0; r < 4; r++) {
    float t = tot[r], tp = tps[r], np_ = npp[r];
    for (int off = 1; off < 16; off <<= 1) {
      t += __shfl_xor(t, off, 16);
      tp += __shfl_xor(tp, off, 16);
      np_ += __shfl_xor(np_, off, 16);
    }
    if (lrow == 0) {
      atomicAdd(&totg[rowg[r]], t);
      atomicAdd(&tposg[rowg[r]], tp);
      atomicAdd(&npg[rowg[r]], np_);
    }
  }
}

// ---------------- per-row finalize + partial loss reduction ----------------
__global__ __launch_bounds__(256) void row_final(const float* __restrict__ totg,
                                                 const float* __restrict__ tposg,
                                                 const float* __restrict__ npg,
                                                 float* __restrict__ scal) {
  int i = blockIdx.x * 256 + threadIdx.x;
  float t = totg[i], tp = tposg[i], np_ = npg[i];
  float per = 0.0f, val = 0.0f;
  if (np_ > 0.0f) {
    per = tp / np_ - __logf(t + 1e-8f);
    val = 1.0f;
  }
  for (int off = 32; off; off >>= 1) {
    per += __shfl_xor(per, off, 64);
    val += __shfl_xor(val, off, 64);
  }
  __shared__ float sp[4], sv[4];
  int wv = threadIdx.x >> 6;
  if ((threadIdx.x & 63) == 0) { sp[wv] = per; sv[wv] = val; }
  __syncthreads();
  if (threadIdx.x == 0) {
    atomicAdd(&scal[0], sp[0] + sp[1] + sp[2] + sp[3]);
    atomicAdd(&scal[1], sv[0] + sv[1] + sv[2] + sv[3]);
  }
}

__global__ void final_k(const float* __restrict__ scal, float* __restrict__ out) {
  float sum = scal[0], nv = scal[1];
  float loss = -(sum / fmaxf(nv, 1.0f)) * 0.5f;  // * TEMPERATURE
  if (nv <= 0.0f) loss = 0.0f;
  if (!__builtin_isfinite(loss)) loss = 0.0f;
  out[0] = loss;
}

extern "C" void kernel_launch(void* const* d_in, const int* in_sizes, int n_in,
                              void* d_out, int out_size, void* d_ws, size_t ws_size,
                              hipStream_t stream) {
  const float* x = (const float*)d_in[0];
  const int* pl = (const int*)d_in[1];
  const int* sl = (const int*)d_in[2];
  char* ws = (char*)d_ws;
  __hip_bfloat16* fb = (__hip_bfloat16*)ws;              // 8192*128*2 = 2,097,152 B
  float* n2 = (float*)(ws + 2097152);                    // 32 KB
  float* totg = (float*)(ws + 2129920);                  // 32 KB
  float* tposg = (float*)(ws + 2162688);                 // 32 KB
  float* npg = (float*)(ws + 2195456);                   // 32 KB
  float* scal = (float*)(ws + 2228224);                  // 8 B

  (void)hipMemsetAsync(totg, 0, 98312, stream);  // totg..scal inclusive

  prep_kernel<<<NN / 4, 256, 0, stream>>>(x, fb, n2);
  fused_kernel<<<dim3(NCH, NN / 64), 256, 0, stream>>>(fb, n2, pl, sl, totg, tposg, npg);
  row_final<<<NN / 256, 256, 0, stream>>>(totg, tposg, npg, scal);
  final_k<<<1, 1, 0, stream>>>(scal, (float*)d_out);
}